// Round 4
// baseline (810.103 us; speedup 1.0000x reference)
//
#include <hip/hip_runtime.h>

typedef __bf16 bf16;
typedef __bf16 bf16x8 __attribute__((ext_vector_type(8)));
typedef __bf16 bf16x4 __attribute__((ext_vector_type(4)));
typedef __bf16 bf16x2 __attribute__((ext_vector_type(2)));
typedef float f32x4 __attribute__((ext_vector_type(4)));

#define MFMA16(a,b,c) __builtin_amdgcn_mfma_f32_16x16x32_bf16((a),(b),(c),0,0,0)

#define NPTS 4096
#define CIN 512
#define DIM 128
#define PH 64
#define HID 512

// ws layout (bytes)
#define OFF_WQS 0u                  // bf16 [128][512] folded w_q@w_sq
#define OFF_WKO (128u*1024u)        // bf16 [128][512] folded w_k@w_so
#define OFF_WVO (256u*1024u)        // bf16 [128][512] folded w_v@w_so
#define OFF_BQS (384u*1024u)        // f32 [128]
#define OFF_BKO (385u*1024u)
#define OFF_BVO (386u*1024u)
#define OFF_S1  (387u*1024u)        // f32 [64]
#define OFF_T1  (388u*1024u)
#define OFF_S2  (389u*1024u)        // f32 [512]
#define OFF_T2  (391u*1024u)        // f32 [512] (ends 393K)
#define OFF_W1P (394u*1024u)        // f32x4 [64] {w0,w1,w2,s1}
#define OFF_CW  (400u*1024u)        // bf16 [wp2 8192 | wa1 65536 | wa2 65536 | we 65536]
#define OFF_QT  (1u<<20)            // bf16 [B][4096][128]
#define OFF_KT  (OFF_QT + (4u<<20))
#define OFF_VT  (OFF_QT + (8u<<20))
#define OFF_IDX (OFF_QT + (12u<<20))
#define WS_NEED (OFF_QT + (13u<<20))

struct P {
  const float* in[31];
  char* ws;
  float* out;
};

__device__ __forceinline__ unsigned pack2(float a, float b){
  union { bf16x2 h; unsigned u; } z; z.h[0]=(bf16)a; z.h[1]=(bf16)b; return z.u;
}
template<int C> __device__ __forceinline__ float rorf(float x){
  return __int_as_float(__builtin_amdgcn_mov_dpp(__float_as_int(x), 0x120|C, 0xF, 0xF, true));
}
__device__ __forceinline__ float red16max(float x){
  x=fmaxf(x,rorf<1>(x)); x=fmaxf(x,rorf<2>(x)); x=fmaxf(x,rorf<4>(x)); x=fmaxf(x,rorf<8>(x)); return x;
}
__device__ __forceinline__ float red16sum(float x){
  x+=rorf<1>(x); x+=rorf<2>(x); x+=rorf<4>(x); x+=rorf<8>(x); return x;
}
// C-layout (rows 4*gs+r at lane gs) -> B-layout (k=8g+j) redistribution across the
// four 16-lane rows. pa=pk[mt_even], pb=pk[mt_odd] (2 u32 each = 4 bf16 rows).
__device__ __forceinline__ bf16x8 redist(unsigned pa0, unsigned pa1, unsigned pb0, unsigned pb1,
                                         int src0, int src1, bool selhi){
  union { unsigned u[4]; bf16x8 v; } z;
  unsigned a0=(unsigned)__shfl((int)pa0,src0), a1=(unsigned)__shfl((int)pa1,src0);
  unsigned a2=(unsigned)__shfl((int)pa0,src1), a3=(unsigned)__shfl((int)pa1,src1);
  unsigned b0=(unsigned)__shfl((int)pb0,src0), b1=(unsigned)__shfl((int)pb1,src0);
  unsigned b2=(unsigned)__shfl((int)pb0,src1), b3=(unsigned)__shfl((int)pb1,src1);
  z.u[0]=selhi?b0:a0; z.u[1]=selhi?b1:a1; z.u[2]=selhi?b2:a2; z.u[3]=selhi?b3:a3;
  return z.v;
}

// ---------------- fold: weight folding + BN precompute + bf16 weight converts ----------------
__global__ __launch_bounds__(256) void k_fold(P p) {
  int tid = blockIdx.x*256 + threadIdx.x;
  char* ws = p.ws;
  if (tid < 196608) {
    int m_id = tid >> 16, o = (tid >> 9) & 127, c = tid & 511;
    const float* A  = m_id==0 ? p.in[9] : (m_id==1 ? p.in[7] : p.in[11]);   // w_q / w_k / w_v
    const float* Bm = (m_id==0) ? p.in[3] : p.in[5];                        // w_sq / w_so
    float acc = 0.f;
    #pragma unroll 8
    for (int m=0;m<128;m++) acc += A[o*128+m] * Bm[m*512+c];
    bf16* outw = (bf16*)(ws + (m_id==0?OFF_WQS: m_id==1?OFF_WKO:OFF_WVO));
    outw[o*512+c] = (bf16)acc;
  } else if (tid < 196992) {
    int t = tid - 196608; int m_id = t >> 7, o = t & 127;
    const float* A  = m_id==0 ? p.in[9] : (m_id==1 ? p.in[7] : p.in[11]);
    const float* bb = (m_id==0) ? p.in[4] : p.in[6];
    const float* bs = m_id==0 ? p.in[10] : (m_id==1 ? p.in[8] : p.in[12]);
    float acc = bs[o];
    for (int m=0;m<128;m++) acc += A[o*128+m] * bb[m];
    float* ob = (float*)(ws + (m_id==0?OFF_BQS: m_id==1?OFF_BKO:OFF_BVO));
    ob[o] = acc;
  } else if (tid < 197056) {
    int i = tid - 196992;
    float s = p.in[15][i] * rsqrtf(p.in[18][i] + 1e-5f);
    ((float*)(ws+OFF_S1))[i] = s;
    ((float*)(ws+OFF_T1))[i] = (p.in[14][i] - p.in[17][i])*s + p.in[16][i];
  } else if (tid < 197568) {
    int i = tid - 197056;
    float s = p.in[23][i] * rsqrtf(p.in[26][i] + 1e-5f);
    ((float*)(ws+OFF_S2))[i] = s;
    ((float*)(ws+OFF_T2))[i] = (p.in[22][i] - p.in[25][i])*s + p.in[24][i];  // b_a1 folded
  } else if (tid < 223168) {
    int e0 = (tid - 197568) * 8;
    const float* src; int base;
    if (e0 < 8192)        { src = p.in[19]; base = 0; }        // w_p2
    else if (e0 < 73728)  { src = p.in[21]; base = 8192; }     // w_a1
    else if (e0 < 139264) { src = p.in[29]; base = 73728; }    // w_a2
    else                  { src = p.in[27]; base = 139264; }   // w_e
    const float* sp = src + (e0 - base);
    f32x4 a = *(const f32x4*)sp, b2 = *(const f32x4*)(sp+4);
    bf16x8 o8;
    o8[0]=(bf16)a[0]; o8[1]=(bf16)a[1]; o8[2]=(bf16)a[2]; o8[3]=(bf16)a[3];
    o8[4]=(bf16)b2[0]; o8[5]=(bf16)b2[1]; o8[6]=(bf16)b2[2]; o8[7]=(bf16)b2[3];
    *(bf16x8*)((bf16*)(ws+OFF_CW) + e0) = o8;
  } else if (tid < 223232) {
    int m = tid - 223168;                                      // pos-MLP packed table
    const float* wp1 = p.in[13];
    float s = p.in[15][m] * rsqrtf(p.in[18][m] + 1e-5f);
    f32x4 v; v[0]=wp1[3*m]; v[1]=wp1[3*m+1]; v[2]=wp1[3*m+2]; v[3]=s;
    *(f32x4*)((char*)(ws+OFF_W1P) + m*16) = v;
  }
}

// ---------------- knn: one wave per query point, keys hoisted to VGPRs ----------------
__global__ __launch_bounds__(256) void k_knn(P p) {
  int lane = threadIdx.x & 63, w = threadIdx.x >> 6;
  int ig = blockIdx.x*4 + w;               // b*4096 + n
  int b = ig >> 12, n = ig & 4095;
  const float* pb = p.in[1] + b*3*NPTS;
  float qx = pb[n], qy = pb[NPTS+n], qz = pb[2*NPTS+n];
  float sqn = __fadd_rn(__fadd_rn(__fmul_rn(qx,qx), __fmul_rn(qy,qy)), __fmul_rn(qz,qz));
  long long keys[64];
  #pragma unroll
  for (int t=0;t<64;t++) {
    int j = t*64 + lane;
    float xj=pb[j], yj=pb[NPTS+j], zj=pb[2*NPTS+j];
    float sqj = __fadd_rn(__fadd_rn(__fmul_rn(xj,xj), __fmul_rn(yj,yj)), __fmul_rn(zj,zj));
    float dot = __fadd_rn(__fadd_rn(__fmul_rn(qx,xj), __fmul_rn(qy,yj)), __fmul_rn(qz,zj));
    float d2 = __fadd_rn(__fsub_rn(sqn, __fmul_rn(2.f,dot)), sqj);
    keys[t] = ((long long)(int)__float_as_uint(d2) << 32) | (long long)j;
  }
  int* op = (int*)(p.ws + OFF_IDX) + ig*16;
  long long prev = -1ll;
  for (int r=0;r<16;r++) {
    long long best = 0x7fffffffffffffffll;
    #pragma unroll
    for (int t=0;t<64;t++) {
      long long k2 = keys[t];
      if (k2 > prev && k2 < best) best = k2;
    }
    #pragma unroll
    for (int off=32; off>0; off>>=1) {
      long long o = __shfl_xor(best, off);
      best = best < o ? best : o;
    }
    prev = best;
    if (lane==0) op[r] = (int)best & 4095;
  }
}

// ---------------- qkv: [128,512]x[512,4096] GEMM -> [n][c] transposed outputs ----------------
__global__ __launch_bounds__(256) void k_qkv(P p) {
  int mat = blockIdx.z, b = blockIdx.y, n0 = blockIdx.x*64;
  int tid = threadIdx.x, lane = tid&63, w = tid>>6;
  const float* in = (mat==0 ? p.in[2] : p.in[0]) + b*CIN*NPTS;
  const bf16* W = (const bf16*)(p.ws + (mat==0?OFF_WQS: mat==1?OFF_WKO:OFF_WVO));
  const float* bias = (const float*)(p.ws + (mat==0?OFF_BQS: mat==1?OFF_BKO:OFF_BVO));
  bf16* outT = (bf16*)(p.ws + (mat==0?OFF_QT: mat==1?OFF_KT:OFF_VT)) + (b*NPTS + n0)*DIM;
  __shared__ __align__(16) bf16 Bl[64*40];   // [64 n][32 c + 8 pad]
  f32x4 acc[8] = {};
  for (int ks=0; ks<16; ks++) {
    int c0 = ks*32;
    {
      int cc = tid>>3, nn0 = (tid&7)*8;
      const float* sp = in + (c0+cc)*NPTS + n0 + nn0;
      f32x4 a = *(const f32x4*)sp, b2 = *(const f32x4*)(sp+4);
      Bl[(nn0+0)*40+cc]=(bf16)a[0];  Bl[(nn0+1)*40+cc]=(bf16)a[1];
      Bl[(nn0+2)*40+cc]=(bf16)a[2];  Bl[(nn0+3)*40+cc]=(bf16)a[3];
      Bl[(nn0+4)*40+cc]=(bf16)b2[0]; Bl[(nn0+5)*40+cc]=(bf16)b2[1];
      Bl[(nn0+6)*40+cc]=(bf16)b2[2]; Bl[(nn0+7)*40+cc]=(bf16)b2[3];
    }
    __syncthreads();
    int ncol = w*16 + (lane&15);
    bf16x8 bfr = *(const bf16x8*)(&Bl[ncol*40 + (lane>>4)*8]);
    #pragma unroll
    for (int ot=0;ot<8;ot++) {
      bf16x8 af = *(const bf16x8*)(W + (ot*16 + (lane&15))*CIN + c0 + (lane>>4)*8);
      acc[ot] = MFMA16(af, bfr, acc[ot]);
    }
    __syncthreads();
  }
  int o0 = (lane>>4)*4;
  int nloc = w*16 + (lane&15);
  #pragma unroll
  for (int ot=0;ot<8;ot++) {
    f32x4 bs = *(const f32x4*)(bias + ot*16 + o0);
    bf16x4 st;
    st[0]=(bf16)(acc[ot][0]+bs[0]); st[1]=(bf16)(acc[ot][1]+bs[1]);
    st[2]=(bf16)(acc[ot][2]+bs[2]); st[3]=(bf16)(acc[ot][3]+bs[3]);
    *(bf16x4*)(outT + nloc*DIM + ot*16 + o0) = st;
  }
}

// ---------------- fused: 8 waves, each owns ONE point (16 neighbor cols), reg-resident ----------------
__global__ __launch_bounds__(512) void k_fused(P p) {
  int bb = blockIdx.y, pt0 = blockIdx.x*8;
  int tid=threadIdx.x, lane=tid&63, w=tid>>6;
  int c = lane&15, g = lane>>4;
  char* ws = p.ws;
  const bf16* qT = (const bf16*)(ws+OFF_QT) + bb*NPTS*DIM;
  const bf16* kT = (const bf16*)(ws+OFF_KT) + bb*NPTS*DIM;
  const bf16* vT = (const bf16*)(ws+OFF_VT) + bb*NPTS*DIM;
  const bf16* wp2b = (const bf16*)(ws+OFF_CW);
  const bf16* wa1b = wp2b + 8192;
  const bf16* wa2b = wa1b + 65536;
  const bf16* web  = wa2b + 65536;
  const float* s2 = (const float*)(ws+OFF_S2);
  const float* t2 = (const float*)(ws+OFF_T2);
  __shared__ __align__(16) bf16 aggl[16*136];  // [16 pt][128 c + 8 pad]

  if (tid < 136) { f32x4 z = {}; *(f32x4*)((char*)aggl + 2176 + tid*16) = z; }  // zero pts 8..15

  int pt = pt0 + w;
  int jc = ((const int*)(ws+OFF_IDX))[(bb*NPTS + pt)*16 + c];
  const float* pb = p.in[1] + bb*3*NPTS;
  float pr0 = pb[pt]-pb[jc], pr1 = pb[NPTS+pt]-pb[NPTS+jc], pr2 = pb[2*NPTS+pt]-pb[2*NPTS+jc];

  // T1 directly in B-frag layout (k = g*8+jj)
  const f32x4* wt4 = (const f32x4*)(ws+OFF_W1P);
  const float* t1t = (const float*)(ws+OFF_T1);
  bf16x8 tb[2];
  #pragma unroll
  for (int ks=0;ks<2;ks++){
    #pragma unroll
    for (int jj=0;jj<8;jj++){
      int m = ks*32 + g*8 + jj;
      f32x4 wv = wt4[m];
      float x = wv[0]*pr0 + wv[1]*pr1 + wv[2]*pr2;
      tb[ks][jj] = (bf16)fmaxf(0.f, x*wv[3] + t1t[m]);
    }
  }
  // PE = w_p2 @ T1 (C-layout frags)
  f32x4 pef[8] = {};
  #pragma unroll
  for (int mt=0;mt<8;mt++){
    #pragma unroll
    for (int ks=0;ks<2;ks++){
      bf16x8 af = *(const bf16x8*)(wp2b + (mt*16+c)*PH + ks*32 + g*8);
      pef[mt] = MFMA16(af, tb[ks], pef[mt]);
    }
  }
  // pk[mt] = bf16-packed (PE + b_p2); kept for phase-4 (v + pe)
  unsigned pk[8][2];
  const float* bp2 = p.in[20];
  #pragma unroll
  for (int mt=0;mt<8;mt++){
    f32x4 bp = *(const f32x4*)(bp2 + mt*16 + g*4);
    pk[mt][0] = pack2(pef[mt][0]+bp[0], pef[mt][1]+bp[1]);
    pk[mt][1] = pack2(pef[mt][2]+bp[2], pef[mt][3]+bp[3]);
  }
  int src0 = c + ((lane&16)<<1);   // c + 32*(g&1)
  int src1 = src0 + 16;
  bool selhi = (g>=2);
  // X = q - k_g + pe, built as B-frags
  bf16x8 xf[4];
  #pragma unroll
  for (int ksx=0;ksx<4;ksx++){
    bf16x8 pe8 = redist(pk[2*ksx][0],pk[2*ksx][1],pk[2*ksx+1][0],pk[2*ksx+1][1],src0,src1,selhi);
    bf16x8 q8 = *(const bf16x8*)(qT + pt*DIM + ksx*32 + g*8);
    bf16x8 k8 = *(const bf16x8*)(kT + jc*DIM + ksx*32 + g*8);
    #pragma unroll
    for (int jj=0;jj<8;jj++)
      xf[ksx][jj] = (bf16)((float)q8[jj] - (float)k8[jj] + (float)pe8[jj]);
  }
  // fused MLP: 8 chunks of 64 hidden, fully in registers, no barriers
  f32x4 S[8] = {};
  #pragma unroll 1
  for (int ch=0;ch<8;ch++){
    f32x4 acc[4] = {};
    #pragma unroll
    for (int ksx=0;ksx<4;ksx++){
      #pragma unroll
      for (int mt2=0;mt2<4;mt2++){
        bf16x8 af = *(const bf16x8*)(wa1b + (ch*64+mt2*16+c)*DIM + ksx*32 + g*8);
        acc[mt2] = MFMA16(af, xf[ksx], acc[mt2]);
      }
    }
    unsigned pk2[4][2];
    #pragma unroll
    for (int mt2=0;mt2<4;mt2++){
      int h0 = ch*64 + mt2*16 + g*4;
      f32x4 sv = *(const f32x4*)(s2 + h0);
      f32x4 tv = *(const f32x4*)(t2 + h0);
      float r0 = fmaxf(0.f, acc[mt2][0]*sv[0]+tv[0]);
      float r1 = fmaxf(0.f, acc[mt2][1]*sv[1]+tv[1]);
      float r2 = fmaxf(0.f, acc[mt2][2]*sv[2]+tv[2]);
      float r3 = fmaxf(0.f, acc[mt2][3]*sv[3]+tv[3]);
      pk2[mt2][0] = pack2(r0,r1); pk2[mt2][1] = pack2(r2,r3);
    }
    bf16x8 hf0 = redist(pk2[0][0],pk2[0][1],pk2[1][0],pk2[1][1],src0,src1,selhi);
    bf16x8 hf1 = redist(pk2[2][0],pk2[2][1],pk2[3][0],pk2[3][1],src0,src1,selhi);
    #pragma unroll
    for (int ot=0;ot<8;ot++){
      bf16x8 af0 = *(const bf16x8*)(wa2b + (ot*16+c)*HID + ch*64 + g*8);
      S[ot] = MFMA16(af0, hf0, S[ot]);
      bf16x8 af1 = *(const bf16x8*)(wa2b + (ot*16+c)*HID + ch*64 + 32 + g*8);
      S[ot] = MFMA16(af1, hf1, S[ot]);
    }
  }
  // softmax over the 16 neighbor lanes (DPP row_ror) + agg = v + sum(attn*pe)
  #pragma unroll
  for (int ot=0;ot<8;ot++){
    bf16x4 v4 = *(const bf16x4*)(vT + pt*DIM + ot*16 + g*4);
    union { unsigned u[2]; bf16x4 h; } pc; pc.u[0]=pk[ot][0]; pc.u[1]=pk[ot][1];
    float agv[4];
    #pragma unroll
    for (int r=0;r<4;r++){
      float mx = red16max(S[ot][r]);
      float e = __expf(S[ot][r]-mx);
      float sm = red16sum(e);
      float at = e/sm;
      float vpe = (float)v4[r] + (float)pc.h[r];
      agv[r] = red16sum(at*vpe);
    }
    if (c==0){
      bf16x4 st; st[0]=(bf16)agv[0]; st[1]=(bf16)agv[1]; st[2]=(bf16)agv[2]; st[3]=(bf16)agv[3];
      *(bf16x4*)(&aggl[w*136 + ot*16 + g*4]) = st;
    }
  }
  __syncthreads();
  // epilogue: out = w_e @ agg + b_e
  {
    const float* be = p.in[28];
    f32x4 acc5[4] = {};
    #pragma unroll
    for (int ksx=0; ksx<4; ksx++) {
      int pcol = lane&15;
      bf16x8 bfr = *(const bf16x8*)(&aggl[pcol*136 + ksx*32 + (lane>>4)*8]);
      #pragma unroll
      for (int i=0;i<4;i++) {
        int e = (w*4+i)*16 + (lane&15);
        bf16x8 af = *(const bf16x8*)(web + e*DIM + ksx*32 + (lane>>4)*8);
        acc5[i] = MFMA16(af, bfr, acc5[i]);
      }
    }
    int ptc = lane&15;
    if (ptc < 8) {
      int n = pt0 + ptc;
      #pragma unroll
      for (int i=0;i<4;i++) {
        int e0 = (w*4+i)*16 + (lane>>4)*4;
        f32x4 be4 = *(const f32x4*)(be + e0);
        #pragma unroll
        for (int r=0;r<4;r++)
          p.out[(bb*CIN + e0+r)*NPTS + n] = acc5[i][r] + be4[r];
      }
    }
  }
}

extern "C" void kernel_launch(void* const* d_in, const int* in_sizes, int n_in,
                              void* d_out, int out_size, void* d_ws, size_t ws_size,
                              hipStream_t stream) {
  if (ws_size < WS_NEED || n_in < 31) return;  // loud failure: output stays zero
  P p;
  for (int i=0;i<31;i++) p.in[i] = (const float*)d_in[i];
  p.ws = (char*)d_ws;
  p.out = (float*)d_out;
  k_fold<<<872, 256, 0, stream>>>(p);
  k_knn<<<4096, 256, 0, stream>>>(p);
  k_qkv<<<dim3(64, 4, 3), 256, 0, stream>>>(p);
  k_fused<<<dim3(512, 4), 512, 0, stream>>>(p);
}

// Round 5
// 483.320 us; speedup vs baseline: 1.6761x; 1.6761x over previous
//
#include <hip/hip_runtime.h>

typedef __bf16 bf16;
typedef __bf16 bf16x8 __attribute__((ext_vector_type(8)));
typedef __bf16 bf16x4 __attribute__((ext_vector_type(4)));
typedef __bf16 bf16x2 __attribute__((ext_vector_type(2)));
typedef float f32x4 __attribute__((ext_vector_type(4)));

#define MFMA16(a,b,c) __builtin_amdgcn_mfma_f32_16x16x32_bf16((a),(b),(c),0,0,0)

#define NPTS 4096
#define CIN 512
#define DIM 128
#define PH 64
#define HID 512

// ws layout (bytes)
#define OFF_WQS 0u                  // bf16 [128][512] folded w_q@w_sq
#define OFF_WKO (128u*1024u)        // bf16 [128][512] folded w_k@w_so
#define OFF_WVO (256u*1024u)        // bf16 [128][512] folded w_v@w_so
#define OFF_BQS (384u*1024u)        // f32 [128]
#define OFF_BKO (385u*1024u)
#define OFF_BVO (386u*1024u)
#define OFF_S1  (387u*1024u)        // f32 [64]
#define OFF_T1  (388u*1024u)
#define OFF_S2  (389u*1024u)        // f32 [512]
#define OFF_T2  (391u*1024u)        // f32 [512]
#define OFF_CW  (400u*1024u)        // bf16 [wp2 8192 | wa1 65536 | wa2 65536 | we 65536]
#define OFF_QT  (1u<<20)            // bf16 [B][4096][128]
#define OFF_KT  (OFF_QT + (4u<<20))
#define OFF_VT  (OFF_QT + (8u<<20))
#define OFF_IDX (OFF_QT + (12u<<20))
#define WS_NEED (OFF_QT + (13u<<20))

struct P {
  const float* in[31];
  char* ws;
  float* out;
};

template<int C> __device__ __forceinline__ float rorf(float x){
  return __int_as_float(__builtin_amdgcn_mov_dpp(__float_as_int(x), 0x120|C, 0xF, 0xF, true));
}
__device__ __forceinline__ float red16max(float x){
  x=fmaxf(x,rorf<1>(x)); x=fmaxf(x,rorf<2>(x)); x=fmaxf(x,rorf<4>(x)); x=fmaxf(x,rorf<8>(x)); return x;
}
__device__ __forceinline__ float red16sum(float x){
  x+=rorf<1>(x); x+=rorf<2>(x); x+=rorf<4>(x); x+=rorf<8>(x); return x;
}

// ---------------- fold: weight folding + BN precompute + bf16 weight converts ----------------
__global__ __launch_bounds__(256) void k_fold(P p) {
  int tid = blockIdx.x*256 + threadIdx.x;
  char* ws = p.ws;
  if (tid < 196608) {
    int m_id = tid >> 16, o = (tid >> 9) & 127, c = tid & 511;
    const float* A  = m_id==0 ? p.in[9] : (m_id==1 ? p.in[7] : p.in[11]);   // w_q / w_k / w_v
    const float* Bm = (m_id==0) ? p.in[3] : p.in[5];                        // w_sq / w_so
    float acc = 0.f;
    #pragma unroll 8
    for (int m=0;m<128;m++) acc += A[o*128+m] * Bm[m*512+c];
    bf16* outw = (bf16*)(ws + (m_id==0?OFF_WQS: m_id==1?OFF_WKO:OFF_WVO));
    outw[o*512+c] = (bf16)acc;
  } else if (tid < 196992) {
    int t = tid - 196608; int m_id = t >> 7, o = t & 127;
    const float* A  = m_id==0 ? p.in[9] : (m_id==1 ? p.in[7] : p.in[11]);
    const float* bb = (m_id==0) ? p.in[4] : p.in[6];
    const float* bs = m_id==0 ? p.in[10] : (m_id==1 ? p.in[8] : p.in[12]);
    float acc = bs[o];
    for (int m=0;m<128;m++) acc += A[o*128+m] * bb[m];
    float* ob = (float*)(ws + (m_id==0?OFF_BQS: m_id==1?OFF_BKO:OFF_BVO));
    ob[o] = acc;
  } else if (tid < 197056) {
    int i = tid - 196992;
    float s = p.in[15][i] * rsqrtf(p.in[18][i] + 1e-5f);
    ((float*)(ws+OFF_S1))[i] = s;
    ((float*)(ws+OFF_T1))[i] = (p.in[14][i] - p.in[17][i])*s + p.in[16][i];
  } else if (tid < 197568) {
    int i = tid - 197056;
    float s = p.in[23][i] * rsqrtf(p.in[26][i] + 1e-5f);
    ((float*)(ws+OFF_S2))[i] = s;
    ((float*)(ws+OFF_T2))[i] = (p.in[22][i] - p.in[25][i])*s + p.in[24][i];  // b_a1 folded
  } else if (tid < 223168) {
    int e0 = (tid - 197568) * 8;
    const float* src; int base;
    if (e0 < 8192)        { src = p.in[19]; base = 0; }        // w_p2
    else if (e0 < 73728)  { src = p.in[21]; base = 8192; }     // w_a1
    else if (e0 < 139264) { src = p.in[29]; base = 73728; }    // w_a2
    else                  { src = p.in[27]; base = 139264; }   // w_e
    const float* sp = src + (e0 - base);
    f32x4 a = *(const f32x4*)sp, b2 = *(const f32x4*)(sp+4);
    bf16x8 o8;
    o8[0]=(bf16)a[0]; o8[1]=(bf16)a[1]; o8[2]=(bf16)a[2]; o8[3]=(bf16)a[3];
    o8[4]=(bf16)b2[0]; o8[5]=(bf16)b2[1]; o8[6]=(bf16)b2[2]; o8[7]=(bf16)b2[3];
    *(bf16x8*)((bf16*)(ws+OFF_CW) + e0) = o8;
  }
}

// ---------------- knn: one wave per query point, u32 ordered keys, jump-table clear ----------------
__global__ __launch_bounds__(256) void k_knn(P p) {
  int lane = threadIdx.x & 63, w = threadIdx.x >> 6;
  int ig = blockIdx.x*4 + w;               // b*4096 + n
  int b = ig >> 12, n = ig & 4095;
  const float* pb = p.in[1] + b*3*NPTS;
  float qx = pb[n], qy = pb[NPTS+n], qz = pb[2*NPTS+n];
  float sqn = __fadd_rn(__fadd_rn(__fmul_rn(qx,qx), __fmul_rn(qy,qy)), __fmul_rn(qz,qz));
  unsigned u[64];
  #pragma unroll
  for (int t=0;t<64;t++) {
    int j = t*64 + lane;
    float xj=pb[j], yj=pb[NPTS+j], zj=pb[2*NPTS+j];
    float sqj = __fadd_rn(__fadd_rn(__fmul_rn(xj,xj), __fmul_rn(yj,yj)), __fmul_rn(zj,zj));
    float dot = __fadd_rn(__fadd_rn(__fmul_rn(qx,xj), __fmul_rn(qy,yj)), __fmul_rn(qz,zj));
    float d2 = __fadd_rn(__fsub_rn(sqn, __fmul_rn(2.f,dot)), sqj);
    unsigned bbits = __float_as_uint(d2);
    // order-preserving float->uint (handles negative-rounded d2)
    u[t] = bbits ^ (((unsigned)((int)bbits >> 31)) | 0x80000000u);
  }
  int* op = (int*)(p.ws + OFF_IDX) + ig*16;
  int tsel_s = 64; bool mine = false;
  #pragma unroll 1
  for (int r=0;r<16;r++) {
    // lazy destructive clear of previous pick (scalar jump table, ~1 VALU op)
    switch (tsel_s) {
#define CLR(T) case T: u[T] = mine ? 0xFFFFFFFFu : u[T]; break;
      CLR(0) CLR(1) CLR(2) CLR(3) CLR(4) CLR(5) CLR(6) CLR(7)
      CLR(8) CLR(9) CLR(10) CLR(11) CLR(12) CLR(13) CLR(14) CLR(15)
      CLR(16) CLR(17) CLR(18) CLR(19) CLR(20) CLR(21) CLR(22) CLR(23)
      CLR(24) CLR(25) CLR(26) CLR(27) CLR(28) CLR(29) CLR(30) CLR(31)
      CLR(32) CLR(33) CLR(34) CLR(35) CLR(36) CLR(37) CLR(38) CLR(39)
      CLR(40) CLR(41) CLR(42) CLR(43) CLR(44) CLR(45) CLR(46) CLR(47)
      CLR(48) CLR(49) CLR(50) CLR(51) CLR(52) CLR(53) CLR(54) CLR(55)
      CLR(56) CLR(57) CLR(58) CLR(59) CLR(60) CLR(61) CLR(62) CLR(63)
#undef CLR
      default: break;
    }
    unsigned vmin = 0xFFFFFFFFu; int tmin = 0;
    #pragma unroll
    for (int t=0;t<64;t++) {
      bool lt = u[t] < vmin;
      vmin = lt ? u[t] : vmin;
      tmin = lt ? t : tmin;
    }
    int jmin = (tmin<<6) | lane;
    #pragma unroll
    for (int off=32; off>0; off>>=1) {
      unsigned vo = (unsigned)__shfl_xor((int)vmin, off);
      int jo = __shfl_xor(jmin, off);
      bool take = (vo < vmin) || (vo == vmin && (unsigned)jo < (unsigned)jmin);
      vmin = take ? vo : vmin;
      jmin = take ? jo : jmin;
    }
    if (lane==0) op[r] = jmin;
    tsel_s = __builtin_amdgcn_readfirstlane(jmin >> 6);
    mine = (lane == (jmin & 63));
  }
}

// ---------------- qkv: [128,512]x[512,4096] GEMM -> [n][c] transposed outputs ----------------
__global__ __launch_bounds__(256) void k_qkv(P p) {
  int mat = blockIdx.z, b = blockIdx.y, n0 = blockIdx.x*64;
  int tid = threadIdx.x, lane = tid&63, w = tid>>6;
  const float* in = (mat==0 ? p.in[2] : p.in[0]) + b*CIN*NPTS;
  const bf16* W = (const bf16*)(p.ws + (mat==0?OFF_WQS: mat==1?OFF_WKO:OFF_WVO));
  const float* bias = (const float*)(p.ws + (mat==0?OFF_BQS: mat==1?OFF_BKO:OFF_BVO));
  bf16* outT = (bf16*)(p.ws + (mat==0?OFF_QT: mat==1?OFF_KT:OFF_VT)) + (b*NPTS + n0)*DIM;
  __shared__ __align__(16) bf16 Bl[64*40];   // [64 n][32 c + 8 pad]
  f32x4 acc[8] = {};
  for (int ks=0; ks<16; ks++) {
    int c0 = ks*32;
    {
      int cc = tid>>3, nn0 = (tid&7)*8;
      const float* sp = in + (c0+cc)*NPTS + n0 + nn0;
      f32x4 a = *(const f32x4*)sp, b2 = *(const f32x4*)(sp+4);
      Bl[(nn0+0)*40+cc]=(bf16)a[0];  Bl[(nn0+1)*40+cc]=(bf16)a[1];
      Bl[(nn0+2)*40+cc]=(bf16)a[2];  Bl[(nn0+3)*40+cc]=(bf16)a[3];
      Bl[(nn0+4)*40+cc]=(bf16)b2[0]; Bl[(nn0+5)*40+cc]=(bf16)b2[1];
      Bl[(nn0+6)*40+cc]=(bf16)b2[2]; Bl[(nn0+7)*40+cc]=(bf16)b2[3];
    }
    __syncthreads();
    int ncol = w*16 + (lane&15);
    bf16x8 bfr = *(const bf16x8*)(&Bl[ncol*40 + (lane>>4)*8]);
    #pragma unroll
    for (int ot=0;ot<8;ot++) {
      bf16x8 af = *(const bf16x8*)(W + (ot*16 + (lane&15))*CIN + c0 + (lane>>4)*8);
      acc[ot] = MFMA16(af, bfr, acc[ot]);
    }
    __syncthreads();
  }
  int o0 = (lane>>4)*4;
  int nloc = w*16 + (lane&15);
  #pragma unroll
  for (int ot=0;ot<8;ot++) {
    f32x4 bs = *(const f32x4*)(bias + ot*16 + o0);
    bf16x4 st;
    st[0]=(bf16)(acc[ot][0]+bs[0]); st[1]=(bf16)(acc[ot][1]+bs[1]);
    st[2]=(bf16)(acc[ot][2]+bs[2]); st[3]=(bf16)(acc[ot][3]+bs[3]);
    *(bf16x4*)(outT + nloc*DIM + ot*16 + o0) = st;
  }
}

// ---------------- fused: per block = 1 batch x 8 points; chunk=128 hidden, 32x64 reg tiles ----------------
__global__ __launch_bounds__(512) void k_fused(P p) {
  int bb = blockIdx.y, pt0 = blockIdx.x*8;
  int tid=threadIdx.x, lane=tid&63, w=tid>>6;
  int c = lane&15, g = lane>>4;
  char* ws = p.ws;
  const bf16* qT = (const bf16*)(ws+OFF_QT) + bb*NPTS*DIM;
  const bf16* kT = (const bf16*)(ws+OFF_KT) + bb*NPTS*DIM;
  const bf16* vT = (const bf16*)(ws+OFF_VT) + bb*NPTS*DIM;
  const int* idxg = (const int*)(ws+OFF_IDX) + (bb*NPTS + pt0)*16;
  const bf16* wp2b = (const bf16*)(ws+OFF_CW);
  const bf16* wa1b = wp2b + 8192;
  const bf16* wa2b = wa1b + 65536;
  const bf16* web  = wa2b + 65536;
  const float* s2 = (const float*)(ws+OFF_S2);
  const float* t2 = (const float*)(ws+OFF_T2);
  __shared__ __align__(16) bf16 Xl[128*136];   // [128 col][128 c + 8 pad]
  __shared__ __align__(16) bf16 HT[128*136];   // T1 then H chunks [128 col][<=128 + pad]
  __shared__ __align__(16) bf16 aggl[16*136];  // [16 pt][128 c + 8 pad]
  __shared__ float prl[128][4];
  __shared__ int idxl[128];

  // phase 0: idx + pos_rel + zero agg pad rows (rows 8..15 = bytes [2176,4352))
  if (tid < 128) {
    int j = idxg[tid] & 4095;
    idxl[tid] = j;
    const float* pb = p.in[1] + bb*3*NPTS;
    int n = pt0 + (tid>>4);
    prl[tid][0] = pb[n]        - pb[j];
    prl[tid][1] = pb[NPTS+n]   - pb[NPTS+j];
    prl[tid][2] = pb[2*NPTS+n] - pb[2*NPTS+j];
  } else if (tid >= 256 && tid < 392) {
    f32x4 z = {};
    *(f32x4*)((char*)aggl + 2176 + (tid-256)*16) = z;
  }
  __syncthreads();

  // phase 1: T1 = relu(bn1(w_p1 @ pos_rel)) -> HT[col][m], m<64
  {
    int col = tid & 127, mb = (tid>>7)*16;
    float r0=prl[col][0], r1=prl[col][1], r2=prl[col][2];
    const float* wp1 = p.in[13];
    const float* s1 = (const float*)(ws+OFF_S1);
    const float* t1 = (const float*)(ws+OFF_T1);
    #pragma unroll
    for (int i=0;i<16;i+=2) {
      int m = mb+i;
      float x0 = wp1[m*3]*r0   + wp1[m*3+1]*r1 + wp1[m*3+2]*r2;
      float x1 = wp1[m*3+3]*r0 + wp1[m*3+4]*r1 + wp1[m*3+5]*r2;
      bf16x2 pk;
      pk[0] = (bf16)fmaxf(0.f, x0*s1[m]   + t1[m]);
      pk[1] = (bf16)fmaxf(0.f, x1*s1[m+1] + t1[m+1]);
      *(bf16x2*)(&HT[col*136 + m]) = pk;
    }
  }
  __syncthreads();

  // phase 2: PE = w_p2 @ T1 + b_p2 ; X = q - k_g + PE -> Xl[col][c]
  {
    f32x4 acc[8] = {};
    int crow = w*16 + c;
    #pragma unroll
    for (int ksx=0; ksx<2; ksx++) {
      int m0 = ksx*32 + g*8;
      bf16x8 af = *(const bf16x8*)(wp2b + crow*PH + m0);
      #pragma unroll
      for (int nt=0; nt<8; nt++) {
        int col = nt*16 + c;
        bf16x8 bfr = *(const bf16x8*)(&HT[col*136 + m0]);
        acc[nt] = MFMA16(af, bfr, acc[nt]);
      }
    }
    int c0 = w*16 + g*4;
    f32x4 bp4 = *(const f32x4*)(p.in[20] + c0);
    #pragma unroll
    for (int nt=0; nt<8; nt++) {
      int col = nt*16 + c;
      int j = idxl[col];
      int n = pt0 + nt;
      bf16x4 q4 = *(const bf16x4*)(qT + n*DIM + c0);
      bf16x4 k4 = *(const bf16x4*)(kT + j*DIM + c0);
      bf16x4 st;
      #pragma unroll
      for (int r=0;r<4;r++)
        st[r] = (bf16)((float)q4[r] - (float)k4[r] + acc[nt][r] + bp4[r]);
      *(bf16x4*)(&Xl[col*136 + c0]) = st;
    }
  }
  __syncthreads();

  // phase 3: fused MLP, 4 chunks of 128 hidden rows; wave tile = 32h x 64col
  f32x4 S[2][4] = {{{},{},{},{}},{{},{},{},{}}};
  int h32 = (w&3)*32, ch64 = (w>>2)*64;
  #pragma unroll 1
  for (int cc4=0; cc4<4; cc4++) {
    int hbase = cc4*128;
    f32x4 acc[2][4] = {{{},{},{},{}},{{},{},{},{}}};
    #pragma unroll
    for (int ksx=0;ksx<4;ksx++) {
      int k0 = ksx*32 + g*8;
      bf16x8 af0 = *(const bf16x8*)(wa1b + (hbase+h32+c)*DIM + k0);
      bf16x8 af1 = *(const bf16x8*)(wa1b + (hbase+h32+16+c)*DIM + k0);
      #pragma unroll
      for (int cg=0;cg<4;cg++) {
        bf16x8 bfr = *(const bf16x8*)(&Xl[(ch64+cg*16+c)*136 + k0]);
        acc[0][cg] = MFMA16(af0, bfr, acc[0][cg]);
        acc[1][cg] = MFMA16(af1, bfr, acc[1][cg]);
      }
    }
    #pragma unroll
    for (int mt2=0;mt2<2;mt2++) {
      int hg = hbase + h32 + mt2*16 + g*4;
      f32x4 sv = *(const f32x4*)(s2+hg), tv = *(const f32x4*)(t2+hg);
      int hloc = h32 + mt2*16 + g*4;
      #pragma unroll
      for (int cg=0;cg<4;cg++) {
        int col = ch64+cg*16+c;
        bf16x4 st;
        st[0]=(bf16)fmaxf(0.f, acc[mt2][cg][0]*sv[0]+tv[0]);
        st[1]=(bf16)fmaxf(0.f, acc[mt2][cg][1]*sv[1]+tv[1]);
        st[2]=(bf16)fmaxf(0.f, acc[mt2][cg][2]*sv[2]+tv[2]);
        st[3]=(bf16)fmaxf(0.f, acc[mt2][cg][3]*sv[3]+tv[3]);
        *(bf16x4*)(&HT[col*136 + hloc]) = st;
      }
    }
    __syncthreads();
    #pragma unroll
    for (int ksx=0;ksx<4;ksx++) {
      int k0 = ksx*32 + g*8;
      bf16x8 af0 = *(const bf16x8*)(wa2b + (h32+c)*HID + hbase + k0);
      bf16x8 af1 = *(const bf16x8*)(wa2b + (h32+16+c)*HID + hbase + k0);
      #pragma unroll
      for (int cg=0;cg<4;cg++) {
        bf16x8 bfr = *(const bf16x8*)(&HT[(ch64+cg*16+c)*136 + k0]);
        S[0][cg] = MFMA16(af0, bfr, S[0][cg]);
        S[1][cg] = MFMA16(af1, bfr, S[1][cg]);
      }
    }
    __syncthreads();
  }

  // phase 4: softmax over the 16 neighbor lanes (DPP) + agg = sum(attn*(v+pe)) -> aggl
  #pragma unroll
  for (int mt2=0;mt2<2;mt2++) {
    #pragma unroll
    for (int cg=0;cg<4;cg++) {
      int ptl = (w>>2)*4 + cg;
      int pt = pt0 + ptl;
      int col = ch64 + cg*16 + c;
      int j = idxl[col];
      int chb = h32 + mt2*16 + g*4;
      bf16x4 x4 = *(const bf16x4*)(&Xl[col*136 + chb]);
      bf16x4 q4 = *(const bf16x4*)(qT + pt*DIM + chb);
      bf16x4 k4 = *(const bf16x4*)(kT + j*DIM + chb);
      bf16x4 v4 = *(const bf16x4*)(vT + pt*DIM + chb);
      float agv[4];
      #pragma unroll
      for (int r=0;r<4;r++) {
        float s = S[mt2][cg][r];
        float mx = red16max(s);
        float e = __expf(s-mx);
        float sm = red16sum(e);
        float at = e/sm;
        float vpe = (float)v4[r] + (float)x4[r] - (float)q4[r] + (float)k4[r];
        agv[r] = red16sum(at*vpe);
      }
      if (c==0) {
        bf16x4 st; st[0]=(bf16)agv[0]; st[1]=(bf16)agv[1]; st[2]=(bf16)agv[2]; st[3]=(bf16)agv[3];
        *(bf16x4*)(&aggl[ptl*136 + chb]) = st;
      }
    }
  }
  __syncthreads();

  // phase 5: out = w_e @ agg + b_e
  {
    const float* be = p.in[28];
    f32x4 acc5[4] = {};
    #pragma unroll
    for (int ksx=0; ksx<4; ksx++) {
      int pcol = c;
      bf16x8 bfr = *(const bf16x8*)(&aggl[pcol*136 + ksx*32 + g*8]);
      #pragma unroll
      for (int i=0;i<4;i++) {
        int e = (w*4+i)*16 + c;
        bf16x8 af = *(const bf16x8*)(web + e*DIM + ksx*32 + g*8);
        acc5[i] = MFMA16(af, bfr, acc5[i]);
      }
    }
    if (c < 8) {
      int n = pt0 + c;
      #pragma unroll
      for (int i=0;i<4;i++) {
        int e0 = (w*4+i)*16 + g*4;
        f32x4 be4 = *(const f32x4*)(be + e0);
        #pragma unroll
        for (int r=0;r<4;r++)
          p.out[(bb*CIN + e0+r)*NPTS + n] = acc5[i][r] + be4[r];
      }
    }
  }
}

extern "C" void kernel_launch(void* const* d_in, const int* in_sizes, int n_in,
                              void* d_out, int out_size, void* d_ws, size_t ws_size,
                              hipStream_t stream) {
  if (ws_size < WS_NEED || n_in < 31) return;  // loud failure: output stays zero
  P p;
  for (int i=0;i<31;i++) p.in[i] = (const float*)d_in[i];
  p.ws = (char*)d_ws;
  p.out = (float*)d_out;
  k_fold<<<872, 256, 0, stream>>>(p);
  k_knn<<<4096, 256, 0, stream>>>(p);
  k_qkv<<<dim3(64, 4, 3), 256, 0, stream>>>(p);
  k_fused<<<dim3(512, 4), 512, 0, stream>>>(p);
}

// Round 6
// 467.893 us; speedup vs baseline: 1.7314x; 1.0330x over previous
//
#include <hip/hip_runtime.h>

typedef __bf16 bf16;
typedef __bf16 bf16x8 __attribute__((ext_vector_type(8)));
typedef __bf16 bf16x4 __attribute__((ext_vector_type(4)));
typedef __bf16 bf16x2 __attribute__((ext_vector_type(2)));
typedef float f32x4 __attribute__((ext_vector_type(4)));

#define MFMA16(a,b,c) __builtin_amdgcn_mfma_f32_16x16x32_bf16((a),(b),(c),0,0,0)

#define NPTS 4096
#define CIN 512
#define DIM 128
#define PH 64
#define HID 512

// ws layout (bytes)
#define OFF_WQS 0u                  // bf16 [128][512] folded w_q@w_sq
#define OFF_WKO (128u*1024u)        // bf16 [128][512] folded w_k@w_so
#define OFF_WVO (256u*1024u)        // bf16 [128][512] folded w_v@w_so
#define OFF_BQS (384u*1024u)        // f32 [128]
#define OFF_BKO (385u*1024u)
#define OFF_BVO (386u*1024u)
#define OFF_S1  (387u*1024u)        // f32 [64]
#define OFF_T1  (388u*1024u)
#define OFF_S2  (389u*1024u)        // f32 [512]
#define OFF_T2  (391u*1024u)        // f32 [512]
#define OFF_CW  (400u*1024u)        // bf16 [wp2 8192 | wa1 65536 | wa2 65536 | we 65536]
#define OFF_QT  (1u<<20)            // bf16 [B][4096][128]
#define OFF_KT  (OFF_QT + (4u<<20))
#define OFF_VT  (OFF_QT + (8u<<20))
#define OFF_IDX (OFF_QT + (12u<<20))
#define WS_NEED (OFF_QT + (13u<<20))

struct P {
  const float* in[31];
  char* ws;
  float* out;
  int ybase;
};

template<int C> __device__ __forceinline__ float rorf(float x){
  return __int_as_float(__builtin_amdgcn_mov_dpp(__float_as_int(x), 0x120|C, 0xF, 0xF, true));
}
__device__ __forceinline__ float red16max(float x){
  x=fmaxf(x,rorf<1>(x)); x=fmaxf(x,rorf<2>(x)); x=fmaxf(x,rorf<4>(x)); x=fmaxf(x,rorf<8>(x)); return x;
}
__device__ __forceinline__ float red16sum(float x){
  x+=rorf<1>(x); x+=rorf<2>(x); x+=rorf<4>(x); x+=rorf<8>(x); return x;
}

// ---------------- fold: weight folding + BN precompute + bf16 weight converts ----------------
__global__ __launch_bounds__(256) void k_fold(P p) {
  int tid = blockIdx.x*256 + threadIdx.x;
  char* ws = p.ws;
  if (tid < 196608) {
    int m_id = tid >> 16, o = (tid >> 9) & 127, c = tid & 511;
    const float* A  = m_id==0 ? p.in[9] : (m_id==1 ? p.in[7] : p.in[11]);   // w_q / w_k / w_v
    const float* Bm = (m_id==0) ? p.in[3] : p.in[5];                        // w_sq / w_so
    float acc = 0.f;
    #pragma unroll 8
    for (int m=0;m<128;m++) acc += A[o*128+m] * Bm[m*512+c];
    bf16* outw = (bf16*)(ws + (m_id==0?OFF_WQS: m_id==1?OFF_WKO:OFF_WVO));
    outw[o*512+c] = (bf16)acc;
  } else if (tid < 196992) {
    int t = tid - 196608; int m_id = t >> 7, o = t & 127;
    const float* A  = m_id==0 ? p.in[9] : (m_id==1 ? p.in[7] : p.in[11]);
    const float* bb = (m_id==0) ? p.in[4] : p.in[6];
    const float* bs = m_id==0 ? p.in[10] : (m_id==1 ? p.in[8] : p.in[12]);
    float acc = bs[o];
    for (int m=0;m<128;m++) acc += A[o*128+m] * bb[m];
    float* ob = (float*)(ws + (m_id==0?OFF_BQS: m_id==1?OFF_BKO:OFF_BVO));
    ob[o] = acc;
  } else if (tid < 197056) {
    int i = tid - 196992;
    float s = p.in[15][i] * rsqrtf(p.in[18][i] + 1e-5f);
    ((float*)(ws+OFF_S1))[i] = s;
    ((float*)(ws+OFF_T1))[i] = (p.in[14][i] - p.in[17][i])*s + p.in[16][i];
  } else if (tid < 197568) {
    int i = tid - 197056;
    float s = p.in[23][i] * rsqrtf(p.in[26][i] + 1e-5f);
    ((float*)(ws+OFF_S2))[i] = s;
    ((float*)(ws+OFF_T2))[i] = (p.in[22][i] - p.in[25][i])*s + p.in[24][i];  // b_a1 folded
  } else if (tid < 223168) {
    int e0 = (tid - 197568) * 8;
    const float* src; int base;
    if (e0 < 8192)        { src = p.in[19]; base = 0; }        // w_p2
    else if (e0 < 73728)  { src = p.in[21]; base = 8192; }     // w_a1
    else if (e0 < 139264) { src = p.in[29]; base = 73728; }    // w_a2
    else                  { src = p.in[27]; base = 139264; }   // w_e
    const float* sp = src + (e0 - base);
    f32x4 a = *(const f32x4*)sp, b2 = *(const f32x4*)(sp+4);
    bf16x8 o8;
    o8[0]=(bf16)a[0]; o8[1]=(bf16)a[1]; o8[2]=(bf16)a[2]; o8[3]=(bf16)a[3];
    o8[4]=(bf16)b2[0]; o8[5]=(bf16)b2[1]; o8[6]=(bf16)b2[2]; o8[7]=(bf16)b2[3];
    *(bf16x8*)((bf16*)(ws+OFF_CW) + e0) = o8;
  }
}

// ---------------- knn: one wave per query point, u32 ordered keys, jump-table clear ----------------
__global__ __launch_bounds__(256) void k_knn(P p) {
  int lane = threadIdx.x & 63, w = threadIdx.x >> 6;
  int ig = blockIdx.x*4 + w;               // b*4096 + n
  int b = ig >> 12, n = ig & 4095;
  const float* pb = p.in[1] + b*3*NPTS;
  float qx = pb[n], qy = pb[NPTS+n], qz = pb[2*NPTS+n];
  float sqn = __fadd_rn(__fadd_rn(__fmul_rn(qx,qx), __fmul_rn(qy,qy)), __fmul_rn(qz,qz));
  unsigned u[64];
  #pragma unroll
  for (int t=0;t<64;t++) {
    int j = t*64 + lane;
    float xj=pb[j], yj=pb[NPTS+j], zj=pb[2*NPTS+j];
    float sqj = __fadd_rn(__fadd_rn(__fmul_rn(xj,xj), __fmul_rn(yj,yj)), __fmul_rn(zj,zj));
    float dot = __fadd_rn(__fadd_rn(__fmul_rn(qx,xj), __fmul_rn(qy,yj)), __fmul_rn(qz,zj));
    float d2 = __fadd_rn(__fsub_rn(sqn, __fmul_rn(2.f,dot)), sqj);
    unsigned bbits = __float_as_uint(d2);
    u[t] = bbits ^ (((unsigned)((int)bbits >> 31)) | 0x80000000u);
  }
  int* op = (int*)(p.ws + OFF_IDX) + ig*16;
  int tsel_s = 64; bool mine = false;
  #pragma unroll 1
  for (int r=0;r<16;r++) {
    switch (tsel_s) {
#define CLR(T) case T: u[T] = mine ? 0xFFFFFFFFu : u[T]; break;
      CLR(0) CLR(1) CLR(2) CLR(3) CLR(4) CLR(5) CLR(6) CLR(7)
      CLR(8) CLR(9) CLR(10) CLR(11) CLR(12) CLR(13) CLR(14) CLR(15)
      CLR(16) CLR(17) CLR(18) CLR(19) CLR(20) CLR(21) CLR(22) CLR(23)
      CLR(24) CLR(25) CLR(26) CLR(27) CLR(28) CLR(29) CLR(30) CLR(31)
      CLR(32) CLR(33) CLR(34) CLR(35) CLR(36) CLR(37) CLR(38) CLR(39)
      CLR(40) CLR(41) CLR(42) CLR(43) CLR(44) CLR(45) CLR(46) CLR(47)
      CLR(48) CLR(49) CLR(50) CLR(51) CLR(52) CLR(53) CLR(54) CLR(55)
      CLR(56) CLR(57) CLR(58) CLR(59) CLR(60) CLR(61) CLR(62) CLR(63)
#undef CLR
      default: break;
    }
    unsigned vmin = 0xFFFFFFFFu; int tmin = 0;
    #pragma unroll
    for (int t=0;t<64;t++) {
      bool lt = u[t] < vmin;
      vmin = lt ? u[t] : vmin;
      tmin = lt ? t : tmin;
    }
    int jmin = (tmin<<6) | lane;
    #pragma unroll
    for (int off=32; off>0; off>>=1) {
      unsigned vo = (unsigned)__shfl_xor((int)vmin, off);
      int jo = __shfl_xor(jmin, off);
      bool take = (vo < vmin) || (vo == vmin && (unsigned)jo < (unsigned)jmin);
      vmin = take ? vo : vmin;
      jmin = take ? jo : jmin;
    }
    if (lane==0) op[r] = jmin;
    tsel_s = __builtin_amdgcn_readfirstlane(jmin >> 6);
    mine = (lane == (jmin & 63));
  }
}

// ---------------- qkv: [128,512]x[512,4096] GEMM -> [n][c] transposed outputs ----------------
__global__ __launch_bounds__(256) void k_qkv(P p) {
  int mat = blockIdx.z, b = blockIdx.y, n0 = blockIdx.x*64;
  int tid = threadIdx.x, lane = tid&63, w = tid>>6;
  const float* in = (mat==0 ? p.in[2] : p.in[0]) + b*CIN*NPTS;
  const bf16* W = (const bf16*)(p.ws + (mat==0?OFF_WQS: mat==1?OFF_WKO:OFF_WVO));
  const float* bias = (const float*)(p.ws + (mat==0?OFF_BQS: mat==1?OFF_BKO:OFF_BVO));
  bf16* outT = (bf16*)(p.ws + (mat==0?OFF_QT: mat==1?OFF_KT:OFF_VT)) + (b*NPTS + n0)*DIM;
  __shared__ __align__(16) bf16 Bl[64*40];   // [64 n][32 c + 8 pad]
  f32x4 acc[8] = {};
  for (int ks=0; ks<16; ks++) {
    int c0 = ks*32;
    {
      int cc = tid>>3, nn0 = (tid&7)*8;
      const float* sp = in + (c0+cc)*NPTS + n0 + nn0;
      f32x4 a = *(const f32x4*)sp, b2 = *(const f32x4*)(sp+4);
      Bl[(nn0+0)*40+cc]=(bf16)a[0];  Bl[(nn0+1)*40+cc]=(bf16)a[1];
      Bl[(nn0+2)*40+cc]=(bf16)a[2];  Bl[(nn0+3)*40+cc]=(bf16)a[3];
      Bl[(nn0+4)*40+cc]=(bf16)b2[0]; Bl[(nn0+5)*40+cc]=(bf16)b2[1];
      Bl[(nn0+6)*40+cc]=(bf16)b2[2]; Bl[(nn0+7)*40+cc]=(bf16)b2[3];
    }
    __syncthreads();
    int ncol = w*16 + (lane&15);
    bf16x8 bfr = *(const bf16x8*)(&Bl[ncol*40 + (lane>>4)*8]);
    #pragma unroll
    for (int ot=0;ot<8;ot++) {
      bf16x8 af = *(const bf16x8*)(W + (ot*16 + (lane&15))*CIN + c0 + (lane>>4)*8);
      acc[ot] = MFMA16(af, bfr, acc[ot]);
    }
    __syncthreads();
  }
  int o0 = (lane>>4)*4;
  int nloc = w*16 + (lane&15);
  #pragma unroll
  for (int ot=0;ot<8;ot++) {
    f32x4 bs = *(const f32x4*)(bias + ot*16 + o0);
    bf16x4 st;
    st[0]=(bf16)(acc[ot][0]+bs[0]); st[1]=(bf16)(acc[ot][1]+bs[1]);
    st[2]=(bf16)(acc[ot][2]+bs[2]); st[3]=(bf16)(acc[ot][3]+bs[3]);
    *(bf16x4*)(outT + nloc*DIM + ot*16 + o0) = st;
  }
}

// ---------------- fused: per block = 1 batch x 8 points; LDS 53.2K -> 3 blocks/CU ----------------
__global__ __launch_bounds__(512) void k_fused(P p) {
  int bb = p.ybase + blockIdx.y, pt0 = blockIdx.x*8;
  int tid=threadIdx.x, lane=tid&63, w=tid>>6;
  int c = lane&15, g = lane>>4;
  char* ws = p.ws;
  const bf16* qT = (const bf16*)(ws+OFF_QT) + bb*NPTS*DIM;
  const bf16* kT = (const bf16*)(ws+OFF_KT) + bb*NPTS*DIM;
  const bf16* vT = (const bf16*)(ws+OFF_VT) + bb*NPTS*DIM;
  const int* idxg = (const int*)(ws+OFF_IDX) + (bb*NPTS + pt0)*16;
  const bf16* wp2b = (const bf16*)(ws+OFF_CW);
  const bf16* wa1b = wp2b + 8192;
  const bf16* wa2b = wa1b + 65536;
  const bf16* web  = wa2b + 65536;
  const float* s2 = (const float*)(ws+OFF_S2);
  const float* t2 = (const float*)(ws+OFF_T2);
  // single LDS arena, manual offsets (order-guaranteed):
  //   Xl  [128][136] bf16 @ 0      (34816 B)
  //   HT  [128][72]  bf16 @ 34816  (18432 B)
  //   aggl [8][136]  bf16 OVERLAYS HT base (dead after last GEMM2 read)
  __shared__ __align__(16) char LB[53248];
  bf16* Xl = (bf16*)LB;
  bf16* HT = (bf16*)(LB + 34816);
  bf16* aggl = (bf16*)(LB + 34816);

  // phase 1: T1 = relu(bn1(w_p1 @ pos_rel)) -> HT[col][m]; wave w owns cols 16w..16w+15
  {
    int col = w*16 + c;
    int j = idxg[col] & 4095;
    const float* pb = p.in[1] + bb*3*NPTS;
    int n = pt0 + w;
    float r0 = pb[n]-pb[j], r1 = pb[NPTS+n]-pb[NPTS+j], r2 = pb[2*NPTS+n]-pb[2*NPTS+j];
    const float* wp1 = p.in[13];
    const float* s1 = (const float*)(ws+OFF_S1);
    const float* t1 = (const float*)(ws+OFF_T1);
    #pragma unroll
    for (int i=0;i<16;i+=2) {
      int m = g*16 + i;
      float x0 = wp1[m*3]*r0   + wp1[m*3+1]*r1 + wp1[m*3+2]*r2;
      float x1 = wp1[m*3+3]*r0 + wp1[m*3+4]*r1 + wp1[m*3+5]*r2;
      bf16x2 pk;
      pk[0] = (bf16)fmaxf(0.f, x0*s1[m]   + t1[m]);
      pk[1] = (bf16)fmaxf(0.f, x1*s1[m+1] + t1[m+1]);
      *(bf16x2*)(&HT[col*72 + m]) = pk;
    }
  }
  __syncthreads();

  // phase 2: PE = w_p2 @ T1 + b_p2 ; X = q - k_g + PE -> Xl[col][c]
  {
    f32x4 acc[8] = {};
    int crow = w*16 + c;
    #pragma unroll
    for (int ksx=0; ksx<2; ksx++) {
      int m0 = ksx*32 + g*8;
      bf16x8 af = *(const bf16x8*)(wp2b + crow*PH + m0);
      #pragma unroll
      for (int nt=0; nt<8; nt++) {
        int col = nt*16 + c;
        bf16x8 bfr = *(const bf16x8*)(&HT[col*72 + m0]);
        acc[nt] = MFMA16(af, bfr, acc[nt]);
      }
    }
    int c0 = w*16 + g*4;
    f32x4 bp4 = *(const f32x4*)(p.in[20] + c0);
    #pragma unroll
    for (int nt=0; nt<8; nt++) {
      int col = nt*16 + c;
      int j = idxg[col] & 4095;
      int n = pt0 + nt;
      bf16x4 q4 = *(const bf16x4*)(qT + n*DIM + c0);
      bf16x4 k4 = *(const bf16x4*)(kT + j*DIM + c0);
      bf16x4 st;
      #pragma unroll
      for (int r=0;r<4;r++)
        st[r] = (bf16)((float)q4[r] - (float)k4[r] + acc[nt][r] + bp4[r]);
      *(bf16x4*)(&Xl[col*136 + c0]) = st;
    }
  }
  __syncthreads();

  // phase 3: fused MLP, 8 chunks of 64 hidden rows (round-3 proven structure)
  f32x4 S[8] = {};
  for (int ch=0; ch<8; ch++) {
    f32x4 acc1[4] = {};
    int mtw = w & 3, nbase = (w>>2)*4;
    int hrow = ch*64 + mtw*16 + c;
    #pragma unroll
    for (int ksx=0; ksx<4; ksx++) {
      bf16x8 af = *(const bf16x8*)(wa1b + hrow*DIM + ksx*32 + g*8);
      #pragma unroll
      for (int i=0; i<4; i++) {
        int col = (nbase+i)*16 + c;
        bf16x8 bfr = *(const bf16x8*)(&Xl[col*136 + ksx*32 + g*8]);
        acc1[i] = MFMA16(af, bfr, acc1[i]);
      }
    }
    int h0 = ch*64 + mtw*16 + g*4;
    int h0loc = mtw*16 + g*4;
    f32x4 sv = *(const f32x4*)(s2 + h0);
    f32x4 tv = *(const f32x4*)(t2 + h0);
    #pragma unroll
    for (int i=0;i<4;i++) {
      int col = (nbase+i)*16 + c;
      bf16x4 st;
      st[0]=(bf16)fmaxf(0.f, acc1[i][0]*sv[0]+tv[0]);
      st[1]=(bf16)fmaxf(0.f, acc1[i][1]*sv[1]+tv[1]);
      st[2]=(bf16)fmaxf(0.f, acc1[i][2]*sv[2]+tv[2]);
      st[3]=(bf16)fmaxf(0.f, acc1[i][3]*sv[3]+tv[3]);
      *(bf16x4*)(&HT[col*72 + h0loc]) = st;
    }
    __syncthreads();
    int orow = w*16 + c;
    #pragma unroll
    for (int ksx=0; ksx<2; ksx++) {
      bf16x8 af = *(const bf16x8*)(wa2b + orow*HID + ch*64 + ksx*32 + g*8);
      #pragma unroll
      for (int nt=0; nt<8; nt++) {
        int col = nt*16 + c;
        bf16x8 bfr = *(const bf16x8*)(&HT[col*72 + ksx*32 + g*8]);
        S[nt] = MFMA16(af, bfr, S[nt]);
      }
    }
    __syncthreads();
  }

  // phase 4: softmax over k (16 lanes, DPP) + agg -> aggl (overlays dead HT)
  {
    int c0 = w*16 + g*4;
    #pragma unroll
    for (int nt=0; nt<8; nt++) {
      f32x4 s = S[nt];
      int col = nt*16 + c;
      int j = idxg[col] & 4095;
      int n = pt0 + nt;
      bf16x4 x4 = *(const bf16x4*)(&Xl[col*136 + c0]);
      bf16x4 q4 = *(const bf16x4*)(qT + n*DIM + c0);
      bf16x4 k4 = *(const bf16x4*)(kT + j*DIM + c0);
      bf16x4 v4 = *(const bf16x4*)(vT + n*DIM + c0);
      float agv[4];
      #pragma unroll
      for (int r=0;r<4;r++) {
        float mx = red16max(s[r]);
        float e = __expf(s[r]-mx);
        float sm = red16sum(e);
        float at = e/sm;
        float vpe = (float)v4[r] + (float)x4[r] - (float)q4[r] + (float)k4[r];
        agv[r] = red16sum(at*vpe);
      }
      if (c==0) {
        bf16x4 st; st[0]=(bf16)agv[0]; st[1]=(bf16)agv[1]; st[2]=(bf16)agv[2]; st[3]=(bf16)agv[3];
        *(bf16x4*)(&aggl[nt*136 + c0]) = st;
      }
    }
  }
  __syncthreads();

  // phase 5: out = w_e @ agg + b_e (B cols 8..15 read in-arena garbage; their C cols are discarded)
  {
    const float* be = p.in[28];
    f32x4 acc5[4] = {};
    #pragma unroll
    for (int ksx=0; ksx<4; ksx++) {
      bf16x8 bfr = *(const bf16x8*)(&aggl[c*136 + ksx*32 + g*8]);
      #pragma unroll
      for (int i=0;i<4;i++) {
        int e = (w*4+i)*16 + c;
        bf16x8 af = *(const bf16x8*)(web + e*DIM + ksx*32 + g*8);
        acc5[i] = MFMA16(af, bfr, acc5[i]);
      }
    }
    if (c < 8) {
      int n = pt0 + c;
      #pragma unroll
      for (int i=0;i<4;i++) {
        int e0 = (w*4+i)*16 + g*4;
        f32x4 be4 = *(const f32x4*)(be + e0);
        #pragma unroll
        for (int r=0;r<4;r++)
          p.out[(bb*CIN + e0+r)*NPTS + n] = acc5[i][r] + be4[r];
      }
    }
  }
}

extern "C" void kernel_launch(void* const* d_in, const int* in_sizes, int n_in,
                              void* d_out, int out_size, void* d_ws, size_t ws_size,
                              hipStream_t stream) {
  if (ws_size < WS_NEED || n_in < 31) return;  // loud failure: output stays zero
  P p;
  for (int i=0;i<31;i++) p.in[i] = (const float*)d_in[i];
  p.ws = (char*)d_ws;
  p.out = (float*)d_out;
  p.ybase = 0;
  k_fold<<<872, 256, 0, stream>>>(p);
  k_knn<<<4096, 256, 0, stream>>>(p);
  k_qkv<<<dim3(64, 4, 3), 256, 0, stream>>>(p);
  k_fused<<<dim3(512, 2), 512, 0, stream>>>(p);
  P p2 = p; p2.ybase = 2;
  k_fused<<<dim3(512, 2), 512, 0, stream>>>(p2);
}